// Round 6
// baseline (382.681 us; speedup 1.0000x reference)
//
#include <hip/hip_runtime.h>

#define NN 100000
#define NE 1600000
#define INF 128
#define HID 64
#define LN_EPS 1e-5f

#define BINB 9
#define BINSZ 512
#define NBIN 196   // ceil(100000/512)
#define FILLB 512  // blocks in k_binfill

#define XPAD 132   // row stride (floats) for sX

typedef unsigned short u16;

// ---------------- CSR build via binned counting sort ----------------

__global__ __launch_bounds__(256) void k_zero(int* __restrict__ bincnt) {
    int i = threadIdx.x;
    if (i < NBIN) bincnt[i] = 0;
}

__global__ __launch_bounds__(256) void k_binhist(const int* __restrict__ dst, int* __restrict__ bincnt) {
    __shared__ int h[NBIN];
    for (int i = threadIdx.x; i < NBIN; i += 256) h[i] = 0;
    __syncthreads();
    int stride = gridDim.x * 256;
    for (int e = blockIdx.x * 256 + threadIdx.x; e < NE; e += stride)
        atomicAdd(&h[dst[e] >> BINB], 1);
    __syncthreads();
    for (int i = threadIdx.x; i < NBIN; i += 256)
        if (h[i]) atomicAdd(&bincnt[i], h[i]);
}

__global__ __launch_bounds__(256) void k_binscan(const int* __restrict__ bincnt, int* __restrict__ binptr,
                                                 int* __restrict__ bincur, int* __restrict__ rowptr) {
    int tid = threadIdx.x, lane = tid & 63, wid = tid >> 6;
    int x = (tid < NBIN) ? bincnt[tid] : 0;
    int v = x;
    #pragma unroll
    for (int d = 1; d < 64; d <<= 1) { int y = __shfl_up(v, d); if (lane >= d) v += y; }
    __shared__ int wsum[4];
    if (lane == 63) wsum[wid] = v;
    __syncthreads();
    int add = 0;
    for (int w = 0; w < wid; ++w) add += wsum[w];
    int excl = v + add - x;
    if (tid < NBIN) { binptr[tid] = excl; bincur[tid] = excl; }
    if (tid == 0) { binptr[NBIN] = NE; rowptr[NN] = NE; }
}

// block-privatized: LDS histogram -> one global atomicAdd per (block,bin) -> LDS-cursor placement
__global__ __launch_bounds__(256) void k_binfill(const int* __restrict__ src, const int* __restrict__ dst,
                                                 int* __restrict__ bincur, unsigned* __restrict__ binpair) {
    __shared__ int cnt[NBIN];
    __shared__ int base[NBIN];
    __shared__ int cur[NBIN];
    int tid = threadIdx.x;
    const int chunk = (NE + FILLB - 1) / FILLB;          // 3125
    int s = blockIdx.x * chunk;
    int t = min(s + chunk, NE);

    for (int i = tid; i < NBIN; i += 256) cnt[i] = 0;
    __syncthreads();
    for (int e = s + tid; e < t; e += 256) atomicAdd(&cnt[dst[e] >> BINB], 1);
    __syncthreads();
    for (int i = tid; i < NBIN; i += 256) {
        int c = cnt[i];
        base[i] = c ? atomicAdd(&bincur[i], c) : 0;
        cur[i] = 0;
    }
    __syncthreads();
    for (int e = s + tid; e < t; e += 256) {
        int d = dst[e];
        int b = d >> BINB;
        int pos = base[b] + atomicAdd(&cur[b], 1);
        binpair[pos] = ((unsigned)src[e] << BINB) | (unsigned)(d & (BINSZ - 1));
    }
}

__global__ __launch_bounds__(256) void k_binsort(const unsigned* __restrict__ binpair,
                                                 const int* __restrict__ binptr,
                                                 int* __restrict__ rowptr, int* __restrict__ eidx) {
    __shared__ int cnt[BINSZ];
    __shared__ int ofs[BINSZ];
    __shared__ int cur[BINSZ];
    int tid = threadIdx.x, lane = tid & 63, wid = tid >> 6;
    int b = blockIdx.x;
    int s = binptr[b], t = binptr[b + 1];

    cnt[tid] = 0; cnt[tid + 256] = 0;
    __syncthreads();
    for (int e = s + tid; e < t; e += 256) atomicAdd(&cnt[binpair[e] & (BINSZ - 1)], 1);
    __syncthreads();

    int a0 = cnt[2 * tid], a1 = cnt[2 * tid + 1];
    int ps = a0 + a1;
    int v = ps;
    #pragma unroll
    for (int d = 1; d < 64; d <<= 1) { int y = __shfl_up(v, d); if (lane >= d) v += y; }
    __shared__ int wsum[4];
    if (lane == 63) wsum[wid] = v;
    __syncthreads();
    int add = 0;
    for (int w = 0; w < wid; ++w) add += wsum[w];
    int excl = v + add - ps;
    ofs[2 * tid] = excl; ofs[2 * tid + 1] = excl + a0;
    cur[2 * tid] = excl; cur[2 * tid + 1] = excl + a0;
    __syncthreads();

    int nodeBase = b << BINB;
    #pragma unroll
    for (int j = 0; j < 2; ++j) {
        int i = tid + j * 256;
        int n = nodeBase + i;
        if (n < NN) rowptr[n] = s + ofs[i];
    }

    for (int e = s + tid; e < t; e += 256) {
        unsigned p = binpair[e];
        int l = p & (BINSZ - 1);
        int pos = s + atomicAdd(&cur[l], 1);
        eidx[pos] = (int)(p >> BINB);
    }
}

// ---------------- fused Linear + LayerNorm + ReLU (lane = node) ----------------
// Block = 4 waves, 64 nodes; wave w owns features [16w,16w+16). W wave-uniform -> scalar.
// Also emits a bf16 (RNE) shadow copy of the output row for the gather kernels.
// BF1: in1 is bf16 (agg from previous gather); else f32.

__device__ __forceinline__ float bf2f(u16 u) { return __uint_as_float((unsigned)u << 16); }

template<bool BF1>
__global__ __launch_bounds__(256) void k_mlp(
    const float* in0, int s0,
    const void* in1v, int s1,
    const float* __restrict__ W,   const float* __restrict__ bias,
    const float* __restrict__ gam, const float* __restrict__ bet,
    float* hout, int ostride, u16* hbf)
{
    __shared__ float sX[64 * XPAD];
    __shared__ float sS[64 * 5];
    __shared__ float sQ[64 * 5];

    const int tid = threadIdx.x, lane = tid & 63;
    const int wid = __builtin_amdgcn_readfirstlane(tid >> 6);
    const int f0 = wid * 16;
    const int node0 = blockIdx.x * 64;

    // stage 64 node-rows (coalesced); clamp tail reads
    #pragma unroll
    for (int j = 0; j < 8; ++j) {
        int f4 = tid + j * 256;
        int nl = f4 >> 5, k4 = f4 & 31;
        int n = node0 + nl;
        if (n >= NN) n = NN - 1;
        float4 v;
        if (k4 < 16) {
            v = *(const float4*)(in0 + (size_t)n * s0 + k4 * 4);
        } else if (!BF1) {
            v = *(const float4*)((const float*)in1v + (size_t)n * s1 + (k4 - 16) * 4);
        } else {
            ushort4 u = *(const ushort4*)((const u16*)in1v + (size_t)n * s1 + (k4 - 16) * 4);
            v = make_float4(bf2f(u.x), bf2f(u.y), bf2f(u.z), bf2f(u.w));
        }
        *(float4*)&sX[nl * XPAD + k4 * 4] = v;
    }

    float bia[16], gma[16], bta[16];
    #pragma unroll
    for (int f = 0; f < 16; ++f) { bia[f] = bias[f0 + f]; gma[f] = gam[f0 + f]; bta[f] = bet[f0 + f]; }

    __syncthreads();

    float acc[16];
    #pragma unroll
    for (int f = 0; f < 16; ++f) acc[f] = bia[f];

    const float* xrow = &sX[lane * XPAD];
    const float* Wf = W + f0;
    #pragma unroll 4
    for (int k4 = 0; k4 < 32; ++k4) {
        float4 xv = *(const float4*)&xrow[k4 * 4];
        const float* Wk = Wf + (size_t)(k4 * 4) * HID;
        #pragma unroll
        for (int i = 0; i < 4; ++i) {
            float xi = (i == 0) ? xv.x : (i == 1) ? xv.y : (i == 2) ? xv.z : xv.w;
            float4 w0 = *(const float4*)(Wk + i * HID + 0);
            float4 w1 = *(const float4*)(Wk + i * HID + 4);
            float4 w2 = *(const float4*)(Wk + i * HID + 8);
            float4 w3 = *(const float4*)(Wk + i * HID + 12);
            acc[0]  = fmaf(xi, w0.x, acc[0]);  acc[1]  = fmaf(xi, w0.y, acc[1]);
            acc[2]  = fmaf(xi, w0.z, acc[2]);  acc[3]  = fmaf(xi, w0.w, acc[3]);
            acc[4]  = fmaf(xi, w1.x, acc[4]);  acc[5]  = fmaf(xi, w1.y, acc[5]);
            acc[6]  = fmaf(xi, w1.z, acc[6]);  acc[7]  = fmaf(xi, w1.w, acc[7]);
            acc[8]  = fmaf(xi, w2.x, acc[8]);  acc[9]  = fmaf(xi, w2.y, acc[9]);
            acc[10] = fmaf(xi, w2.z, acc[10]); acc[11] = fmaf(xi, w2.w, acc[11]);
            acc[12] = fmaf(xi, w3.x, acc[12]); acc[13] = fmaf(xi, w3.y, acc[13]);
            acc[14] = fmaf(xi, w3.z, acc[14]); acc[15] = fmaf(xi, w3.w, acc[15]);
        }
    }

    float s = 0.f, q = 0.f;
    #pragma unroll
    for (int f = 0; f < 16; ++f) { s += acc[f]; q += acc[f] * acc[f]; }
    sS[lane * 5 + wid] = s;
    sQ[lane * 5 + wid] = q;
    __syncthreads();
    float ts = 0.f, tq = 0.f;
    #pragma unroll
    for (int w = 0; w < 4; ++w) { ts += sS[lane * 5 + w]; tq += sQ[lane * 5 + w]; }
    float mu  = ts * 0.015625f;
    float var = fmaxf(tq * 0.015625f - mu * mu, 0.f);
    float rs  = rsqrtf(var + LN_EPS);

    int n = node0 + lane;
    if (n < NN) {
        float o[16];
        #pragma unroll
        for (int f = 0; f < 16; ++f)
            o[f] = fmaxf((acc[f] - mu) * rs * gma[f] + bta[f], 0.f);
        float* op = hout + (size_t)n * ostride + f0;
        *(float4*)(op + 0)  = make_float4(o[0], o[1], o[2], o[3]);
        *(float4*)(op + 4)  = make_float4(o[4], o[5], o[6], o[7]);
        *(float4*)(op + 8)  = make_float4(o[8], o[9], o[10], o[11]);
        *(float4*)(op + 12) = make_float4(o[12], o[13], o[14], o[15]);

        // bf16 shadow (RNE); o >= 0
        unsigned pk[8];
        #pragma unroll
        for (int i = 0; i < 8; ++i) {
            unsigned ua = __float_as_uint(o[2 * i]);
            unsigned ub = __float_as_uint(o[2 * i + 1]);
            ua = (ua + 0x7FFFu + ((ua >> 16) & 1u)) >> 16;
            ub = (ub + 0x7FFFu + ((ub >> 16) & 1u)) >> 16;
            pk[i] = ua | (ub << 16);
        }
        uint4* bp = (uint4*)(hbf + (size_t)n * HID + f0);
        bp[0] = make_uint4(pk[0], pk[1], pk[2], pk[3]);
        bp[1] = make_uint4(pk[4], pk[5], pk[6], pk[7]);
    }
}

// ---------------- per-dst segment max over bf16 rows ----------------
// Post-ReLU values >= 0: bf16 bit pattern order == numeric order -> integer max.

__global__ __launch_bounds__(256) void k_gather_bb(
    const u16* __restrict__ hb, const int* __restrict__ rowptr,
    const int* __restrict__ eidx, u16* __restrict__ aggb)
{
    int lane = threadIdx.x & 63;
    int n = blockIdx.x * 4 + (threadIdx.x >> 6);
    if (n >= NN) return;
    int start = rowptr[n], end = rowptr[n + 1];
    unsigned m;
    if (start == end) {
        m = hb[(size_t)n * HID + lane];
    } else {
        m = 0u;
        int e = start;
        for (; e + 4 <= end; e += 4) {
            int i0 = eidx[e], i1 = eidx[e + 1], i2 = eidx[e + 2], i3 = eidx[e + 3];
            unsigned a = hb[(size_t)i0 * HID + lane], b = hb[(size_t)i1 * HID + lane];
            unsigned c = hb[(size_t)i2 * HID + lane], d = hb[(size_t)i3 * HID + lane];
            m = max(m, max(max(a, b), max(c, d)));
        }
        for (; e < end; ++e) m = max(m, (unsigned)hb[(size_t)eidx[e] * HID + lane]);
    }
    aggb[(size_t)n * HID + lane] = (u16)m;
}

// final layer: read bf16 rows, write f32 agg into out[n][64:128]; self-copy from f32 h half.
__global__ __launch_bounds__(256) void k_gather_bf(
    const u16* __restrict__ hb, const int* __restrict__ rowptr,
    const int* __restrict__ eidx, float* __restrict__ out)
{
    int lane = threadIdx.x & 63;
    int n = blockIdx.x * 4 + (threadIdx.x >> 6);
    if (n >= NN) return;
    int start = rowptr[n], end = rowptr[n + 1];
    float v;
    if (start == end) {
        v = out[(size_t)n * 128 + lane];   // exact f32 self feature
    } else {
        unsigned m = 0u;
        int e = start;
        for (; e + 4 <= end; e += 4) {
            int i0 = eidx[e], i1 = eidx[e + 1], i2 = eidx[e + 2], i3 = eidx[e + 3];
            unsigned a = hb[(size_t)i0 * HID + lane], b = hb[(size_t)i1 * HID + lane];
            unsigned c = hb[(size_t)i2 * HID + lane], d = hb[(size_t)i3 * HID + lane];
            m = max(m, max(max(a, b), max(c, d)));
        }
        for (; e < end; ++e) m = max(m, (unsigned)hb[(size_t)eidx[e] * HID + lane]);
        v = __uint_as_float(m << 16);
    }
    out[(size_t)n * 128 + 64 + lane] = v;
}

// ---------------- launch ----------------

extern "C" void kernel_launch(void* const* d_in, const int* in_sizes, int n_in,
                              void* d_out, int out_size, void* d_ws, size_t ws_size,
                              hipStream_t stream) {
    const float* inputs = (const float*)d_in[0];
    const int*   src    = (const int*)d_in[1];
    const int*   dst    = (const int*)d_in[2];
    const float* Ws     = (const float*)d_in[3];
    const float* bs     = (const float*)d_in[4];
    const float* gs     = (const float*)d_in[5];
    const float* bes    = (const float*)d_in[6];
    float* out = (float*)d_out;

    char* w = (char*)d_ws;
    int* bincnt = (int*)w; w += 256 * 4;
    int* binptr = (int*)w; w += 256 * 4;
    int* bincur = (int*)w; w += 256 * 4;
    int* rowptr = (int*)w; w += (size_t)(NN + 1) * 4;
    int* eidx   = (int*)w; w += (size_t)NE * 4;
    uintptr_t a = (uintptr_t)w; a = (a + 255) & ~(uintptr_t)255; w = (char*)a;
    float* hA   = (float*)w; w += (size_t)NN * HID * 4;   // 25.6 MB
    u16*   hbf  = (u16*)w;  w += (size_t)NN * HID * 2;    // 12.8 MB
    u16*   aggb = (u16*)w;  w += (size_t)NN * HID * 2;    // 12.8 MB
    // binpair (6.4 MB) aliases aggb region: dead before aggb's first write (stream-ordered)
    unsigned* binpair = (unsigned*)aggb;

    const int MLPB = (NN + 63) / 64;   // 1563

    // CSR build (graph is layer-invariant within a call)
    k_zero   <<<1,     256, 0, stream>>>(bincnt);
    k_binhist<<<391,   256, 0, stream>>>(dst, bincnt);
    k_binscan<<<1,     256, 0, stream>>>(bincnt, binptr, bincur, rowptr);
    k_binfill<<<FILLB, 256, 0, stream>>>(src, dst, bincur, binpair);
    k_binsort<<<NBIN,  256, 0, stream>>>(binpair, binptr, rowptr, eidx);

    // layer 0
    k_mlp<false><<<MLPB, 256, 0, stream>>>(inputs, INF, inputs + HID, INF,
                                           Ws, bs, gs, bes, hA, HID, hbf);
    k_gather_bb <<<25000, 256, 0, stream>>>(hbf, rowptr, eidx, aggb);
    // layer 1 (h in-place)
    k_mlp<true> <<<MLPB, 256, 0, stream>>>(hA, HID, aggb, HID,
                                           Ws + 8192, bs + 64, gs + 64, bes + 64, hA, HID, hbf);
    k_gather_bb <<<25000, 256, 0, stream>>>(hbf, rowptr, eidx, aggb);
    // layer 2 -> out interleaved
    k_mlp<true> <<<MLPB, 256, 0, stream>>>(hA, HID, aggb, HID,
                                           Ws + 16384, bs + 128, gs + 128, bes + 128, out, 2 * HID, hbf);
    k_gather_bf <<<25000, 256, 0, stream>>>(hbf, rowptr, eidx, out);
}

// Round 8
// 262.273 us; speedup vs baseline: 1.4591x; 1.4591x over previous
//
#include <hip/hip_runtime.h>

#define NN 100000
#define NE 1600000
#define INF 128
#define HID 64
#define LN_EPS 1e-5f

#define BINB 9
#define BINSZ 512
#define NBIN 196
#define FILLB 512

typedef unsigned short u16;
typedef __attribute__((ext_vector_type(8))) short bf16x8;
typedef __attribute__((ext_vector_type(4))) float f32x4;

#define SAP 136   // padded LDS row stride (bf16 elems): 272B, 16B-aligned, conflict-free b128

__device__ __forceinline__ u16 f2bf(float f) {
    unsigned u = __float_as_uint(f);
    return (u16)((u + 0x7FFFu + ((u >> 16) & 1u)) >> 16);
}
__device__ __forceinline__ unsigned pack2bf(float a, float b) {
    unsigned ua = __float_as_uint(a), ub = __float_as_uint(b);
    ua = (ua + 0x7FFFu + ((ua >> 16) & 1u)) >> 16;
    ub = (ub + 0x7FFFu + ((ub >> 16) & 1u)) >> 16;
    return ua | (ub << 16);
}

// ---------------- CSR build via binned counting sort ----------------

__global__ __launch_bounds__(256) void k_zero(int* __restrict__ bincnt) {
    int i = threadIdx.x;
    if (i < NBIN) bincnt[i] = 0;
}

__global__ __launch_bounds__(256) void k_binhist(const int* __restrict__ dst, int* __restrict__ bincnt) {
    __shared__ int h[NBIN];
    for (int i = threadIdx.x; i < NBIN; i += 256) h[i] = 0;
    __syncthreads();
    int stride = gridDim.x * 256;
    for (int e = blockIdx.x * 256 + threadIdx.x; e < NE; e += stride)
        atomicAdd(&h[dst[e] >> BINB], 1);
    __syncthreads();
    for (int i = threadIdx.x; i < NBIN; i += 256)
        if (h[i]) atomicAdd(&bincnt[i], h[i]);
}

__global__ __launch_bounds__(256) void k_binscan(const int* __restrict__ bincnt, int* __restrict__ binptr,
                                                 int* __restrict__ bincur, int* __restrict__ rowptr) {
    int tid = threadIdx.x, lane = tid & 63, wid = tid >> 6;
    int x = (tid < NBIN) ? bincnt[tid] : 0;
    int v = x;
    #pragma unroll
    for (int d = 1; d < 64; d <<= 1) { int y = __shfl_up(v, d); if (lane >= d) v += y; }
    __shared__ int wsum[4];
    if (lane == 63) wsum[wid] = v;
    __syncthreads();
    int add = 0;
    for (int w = 0; w < wid; ++w) add += wsum[w];
    int excl = v + add - x;
    if (tid < NBIN) { binptr[tid] = excl; bincur[tid] = excl; }
    if (tid == 0) { binptr[NBIN] = NE; rowptr[NN] = NE; }
}

__global__ __launch_bounds__(256) void k_binfill(const int* __restrict__ src, const int* __restrict__ dst,
                                                 int* __restrict__ bincur, unsigned* __restrict__ binpair) {
    __shared__ int cnt[NBIN];
    __shared__ int base[NBIN];
    __shared__ int cur[NBIN];
    int tid = threadIdx.x;
    const int chunk = (NE + FILLB - 1) / FILLB;
    int s = blockIdx.x * chunk;
    int t = min(s + chunk, NE);

    for (int i = tid; i < NBIN; i += 256) cnt[i] = 0;
    __syncthreads();
    for (int e = s + tid; e < t; e += 256) atomicAdd(&cnt[dst[e] >> BINB], 1);
    __syncthreads();
    for (int i = tid; i < NBIN; i += 256) {
        int c = cnt[i];
        base[i] = c ? atomicAdd(&bincur[i], c) : 0;
        cur[i] = 0;
    }
    __syncthreads();
    for (int e = s + tid; e < t; e += 256) {
        int d = dst[e];
        int b = d >> BINB;
        int pos = base[b] + atomicAdd(&cur[b], 1);
        binpair[pos] = ((unsigned)src[e] << BINB) | (unsigned)(d & (BINSZ - 1));
    }
}

__global__ __launch_bounds__(256) void k_binsort(const unsigned* __restrict__ binpair,
                                                 const int* __restrict__ binptr,
                                                 int* __restrict__ rowptr, int* __restrict__ eidx) {
    __shared__ int cnt[BINSZ];
    __shared__ int ofs[BINSZ];
    __shared__ int cur[BINSZ];
    int tid = threadIdx.x, lane = tid & 63, wid = tid >> 6;
    int b = blockIdx.x;
    int s = binptr[b], t = binptr[b + 1];

    cnt[tid] = 0; cnt[tid + 256] = 0;
    __syncthreads();
    for (int e = s + tid; e < t; e += 256) atomicAdd(&cnt[binpair[e] & (BINSZ - 1)], 1);
    __syncthreads();

    int a0 = cnt[2 * tid], a1 = cnt[2 * tid + 1];
    int ps = a0 + a1;
    int v = ps;
    #pragma unroll
    for (int d = 1; d < 64; d <<= 1) { int y = __shfl_up(v, d); if (lane >= d) v += y; }
    __shared__ int wsum[4];
    if (lane == 63) wsum[wid] = v;
    __syncthreads();
    int add = 0;
    for (int w = 0; w < wid; ++w) add += wsum[w];
    int excl = v + add - ps;
    ofs[2 * tid] = excl; ofs[2 * tid + 1] = excl + a0;
    cur[2 * tid] = excl; cur[2 * tid + 1] = excl + a0;
    __syncthreads();

    int nodeBase = b << BINB;
    #pragma unroll
    for (int j = 0; j < 2; ++j) {
        int i = tid + j * 256;
        int n = nodeBase + i;
        if (n < NN) rowptr[n] = s + ofs[i];
    }

    for (int e = s + tid; e < t; e += 256) {
        unsigned p = binpair[e];
        int l = p & (BINSZ - 1);
        int pos = s + atomicAdd(&cur[l], 1);
        eidx[pos] = (int)(p >> BINB);
    }
}

// ---------------- W convert: f32 [128][64] -> bf16 transposed [64][128] ----------------

__global__ __launch_bounds__(256) void k_wconv(const float* __restrict__ Ws, u16* __restrict__ wtb) {
    int L = blockIdx.x, tid = threadIdx.x;
    int c = tid & 63, k0 = (tid >> 6) * 32;
    const float* W = Ws + (size_t)L * INF * HID;
    alignas(16) u16 tmp[32];
    #pragma unroll
    for (int k = 0; k < 32; ++k) tmp[k] = f2bf(W[(size_t)(k0 + k) * HID + c]);
    u16* dstp = wtb + (size_t)L * HID * INF + (size_t)c * INF + k0;
    #pragma unroll
    for (int j = 0; j < 4; ++j)
        *(uint4*)(dstp + j * 8) = *(uint4*)&tmp[j * 8];   // FIX: uint4 (8 u16), was uint2
}

// ---------------- MFMA Linear + LayerNorm + ReLU ----------------
// Block = 4 waves, 64 nodes (wave w owns nodes w*16..w*16+15, ALL 64 features).
// KIND 0: x from f32 inputs[n][128]; KIND 1: x from xbf[n][128] bf16;
// KIND 2: same as 1 + full-precision f32 h stored to out[n][0:64].
// All KINDs write bf16 h into xbf[n][0:64] (in-place safe: node-wise map, staged first).

template<int KIND>
__global__ __launch_bounds__(256) void k_mlp(
    const float* __restrict__ fin,
    u16* xbf,
    const u16* __restrict__ wtb,
    const float* __restrict__ bias, const float* __restrict__ gam, const float* __restrict__ bet,
    float* __restrict__ fout)
{
    __shared__ u16 sA[64 * SAP];   // x tile   (bf16, padded rows)
    __shared__ u16 sB[64 * SAP];   // Wt tile  (feature-major: [c][k])

    const int tid = threadIdx.x, lane = tid & 63;
    const int w = __builtin_amdgcn_readfirstlane(tid >> 6);
    const int node0 = blockIdx.x * 64;

    // ---- stage x ----
    if (KIND == 0) {
        #pragma unroll
        for (int j = 0; j < 8; ++j) {
            int f4 = tid + j * 256;            // 2048 float4 chunks
            int nl = f4 >> 5, k4 = f4 & 31;
            int n = node0 + nl; if (n >= NN) n = NN - 1;
            float4 v = *(const float4*)(fin + (size_t)n * INF + k4 * 4);
            *(uint2*)&sA[nl * SAP + k4 * 4] = make_uint2(pack2bf(v.x, v.y), pack2bf(v.z, v.w));
        }
    } else {
        #pragma unroll
        for (int j = 0; j < 4; ++j) {
            int ch = tid + j * 256;            // 1024 b128 chunks
            int nl = ch >> 4, c8 = ch & 15;
            int n = node0 + nl; if (n >= NN) n = NN - 1;
            *(uint4*)&sA[nl * SAP + c8 * 8] = *(const uint4*)(xbf + (size_t)n * INF + c8 * 8);
        }
    }
    // ---- stage Wt ----
    #pragma unroll
    for (int j = 0; j < 4; ++j) {
        int ch = tid + j * 256;
        int r = ch >> 4, k8 = ch & 15;
        *(uint4*)&sB[r * SAP + k8 * 8] = *(const uint4*)(wtb + (size_t)r * INF + k8 * 8);
    }

    // per-lane feature params: c = nt*16 + (lane&15)
    const int cl = lane & 15;
    float bC[4], gC[4], tC[4];
    #pragma unroll
    for (int nt = 0; nt < 4; ++nt) {
        int c = nt * 16 + cl;
        bC[nt] = bias[c]; gC[nt] = gam[c]; tC[nt] = bet[c];
    }

    __syncthreads();

    // ---- MFMA: D[node][feat], wave strip = 16 nodes ----
    f32x4 acc[4] = {(f32x4)0.f, (f32x4)0.f, (f32x4)0.f, (f32x4)0.f};
    const int kg = (lane >> 4) * 8;            // k-chunk within 32
    #pragma unroll
    for (int kk = 0; kk < 4; ++kk) {
        bf16x8 a = *(const bf16x8*)&sA[(w * 16 + cl) * SAP + kk * 32 + kg];
        #pragma unroll
        for (int nt = 0; nt < 4; ++nt) {
            bf16x8 b = *(const bf16x8*)&sB[(nt * 16 + cl) * SAP + kk * 32 + kg];
            acc[nt] = __builtin_amdgcn_mfma_f32_16x16x32_bf16(a, b, acc[nt], 0, 0, 0);
        }
    }

    // ---- bias + LayerNorm stats (per node = per D-row, in-wave) ----
    #pragma unroll
    for (int nt = 0; nt < 4; ++nt)
        #pragma unroll
        for (int r = 0; r < 4; ++r) acc[nt][r] += bC[nt];

    float mu[4], rs[4];
    #pragma unroll
    for (int r = 0; r < 4; ++r) {
        float s = acc[0][r] + acc[1][r] + acc[2][r] + acc[3][r];
        float q = acc[0][r]*acc[0][r] + acc[1][r]*acc[1][r] + acc[2][r]*acc[2][r] + acc[3][r]*acc[3][r];
        #pragma unroll
        for (int m = 1; m < 16; m <<= 1) { s += __shfl_xor(s, m); q += __shfl_xor(q, m); }
        mu[r] = s * 0.015625f;
        float var = fmaxf(q * 0.015625f - mu[r] * mu[r], 0.f);
        rs[r] = rsqrtf(var + LN_EPS);
    }

    // ---- epilogue: relu((acc-mu)*rs*g + b); write bf16 to own LDS strip; opt f32 out ----
    #pragma unroll
    for (int nt = 0; nt < 4; ++nt) {
        int c = nt * 16 + cl;
        #pragma unroll
        for (int r = 0; r < 4; ++r) {
            int row = w * 16 + (lane >> 4) * 4 + r;     // node offset in block
            float o = fmaxf((acc[nt][r] - mu[r]) * rs[r] * gC[nt] + tC[nt], 0.f);
            sA[row * SAP + c] = f2bf(o);
            if (KIND == 2) {
                int n = node0 + row;
                if (n < NN) fout[(size_t)n * 128 + c] = o;
            }
        }
    }

    // ---- copy own strip (16 rows x 64 bf16) to xbf h-half, coalesced ----
    #pragma unroll
    for (int i = 0; i < 2; ++i) {
        int ch = lane + i * 64;                 // 128 chunks
        int r16 = ch >> 3, c8 = ch & 7;
        int row = w * 16 + r16;
        int n = node0 + row;
        if (n < NN)
            *(uint4*)(xbf + (size_t)n * INF + c8 * 8) = *(const uint4*)&sA[row * SAP + c8 * 8];
    }
}

// ---------------- per-dst segment max over bf16 rows (stride 128) ----------------

__global__ __launch_bounds__(256) void k_gather_bb(
    const u16* __restrict__ hb, const int* __restrict__ rowptr,
    const int* __restrict__ eidx, u16* __restrict__ aggb)
{
    int lane = threadIdx.x & 63;
    int n = blockIdx.x * 4 + (threadIdx.x >> 6);
    if (n >= NN) return;
    int start = rowptr[n], end = rowptr[n + 1];
    unsigned m;
    if (start == end) {
        m = hb[(size_t)n * 128 + lane];
    } else {
        m = 0u;
        int e = start;
        for (; e + 8 <= end; e += 8) {
            unsigned v0 = hb[(size_t)eidx[e]     * 128 + lane], v1 = hb[(size_t)eidx[e + 1] * 128 + lane];
            unsigned v2 = hb[(size_t)eidx[e + 2] * 128 + lane], v3 = hb[(size_t)eidx[e + 3] * 128 + lane];
            unsigned v4 = hb[(size_t)eidx[e + 4] * 128 + lane], v5 = hb[(size_t)eidx[e + 5] * 128 + lane];
            unsigned v6 = hb[(size_t)eidx[e + 6] * 128 + lane], v7 = hb[(size_t)eidx[e + 7] * 128 + lane];
            m = max(m, max(max(max(v0, v1), max(v2, v3)), max(max(v4, v5), max(v6, v7))));
        }
        for (; e < end; ++e) m = max(m, (unsigned)hb[(size_t)eidx[e] * 128 + lane]);
    }
    aggb[(size_t)n * 128 + lane] = (u16)m;
}

__global__ __launch_bounds__(256) void k_gather_bf(
    const u16* __restrict__ hb, const int* __restrict__ rowptr,
    const int* __restrict__ eidx, float* __restrict__ out)
{
    int lane = threadIdx.x & 63;
    int n = blockIdx.x * 4 + (threadIdx.x >> 6);
    if (n >= NN) return;
    int start = rowptr[n], end = rowptr[n + 1];
    float v;
    if (start == end) {
        v = out[(size_t)n * 128 + lane];           // exact f32 self feature
    } else {
        unsigned m = 0u;
        int e = start;
        for (; e + 8 <= end; e += 8) {
            unsigned v0 = hb[(size_t)eidx[e]     * 128 + lane], v1 = hb[(size_t)eidx[e + 1] * 128 + lane];
            unsigned v2 = hb[(size_t)eidx[e + 2] * 128 + lane], v3 = hb[(size_t)eidx[e + 3] * 128 + lane];
            unsigned v4 = hb[(size_t)eidx[e + 4] * 128 + lane], v5 = hb[(size_t)eidx[e + 5] * 128 + lane];
            unsigned v6 = hb[(size_t)eidx[e + 6] * 128 + lane], v7 = hb[(size_t)eidx[e + 7] * 128 + lane];
            m = max(m, max(max(max(v0, v1), max(v2, v3)), max(max(v4, v5), max(v6, v7))));
        }
        for (; e < end; ++e) m = max(m, (unsigned)hb[(size_t)eidx[e] * 128 + lane]);
        v = __uint_as_float(m << 16);
    }
    out[(size_t)n * 128 + 64 + lane] = v;
}

// ---------------- launch ----------------

extern "C" void kernel_launch(void* const* d_in, const int* in_sizes, int n_in,
                              void* d_out, int out_size, void* d_ws, size_t ws_size,
                              hipStream_t stream) {
    const float* inputs = (const float*)d_in[0];
    const int*   src    = (const int*)d_in[1];
    const int*   dst    = (const int*)d_in[2];
    const float* Ws     = (const float*)d_in[3];
    const float* bs     = (const float*)d_in[4];
    const float* gs     = (const float*)d_in[5];
    const float* bes    = (const float*)d_in[6];
    float* out = (float*)d_out;

    char* w = (char*)d_ws;
    int* bincnt = (int*)w; w += 256 * 4;
    int* binptr = (int*)w; w += 256 * 4;
    int* bincur = (int*)w; w += 256 * 4;
    int* rowptr = (int*)w; w += (size_t)(NN + 1) * 4;
    int* eidx   = (int*)w; w += (size_t)NE * 4;
    uintptr_t a = (uintptr_t)w; a = (a + 255) & ~(uintptr_t)255; w = (char*)a;
    u16* wtb     = (u16*)w; w += 3 * (size_t)INF * HID * 2;          // 48 KB
    u16* xbf     = (u16*)w; w += (size_t)NN * INF * 2;               // 25.6 MB  [h|agg] bf16
    unsigned* binpair = (unsigned*)w; w += (size_t)NE * 4;           // 6.4 MB

    const int MLPB = (NN + 63) / 64;   // 1563

    // CSR build
    k_zero   <<<1,     256, 0, stream>>>(bincnt);
    k_binhist<<<391,   256, 0, stream>>>(dst, bincnt);
    k_binscan<<<1,     256, 0, stream>>>(bincnt, binptr, bincur, rowptr);
    k_binfill<<<FILLB, 256, 0, stream>>>(src, dst, bincur, binpair);
    k_binsort<<<NBIN,  256, 0, stream>>>(binpair, binptr, rowptr, eidx);

    // weights -> bf16 transposed
    k_wconv<<<3, 256, 0, stream>>>(Ws, wtb);

    // layer 0
    k_mlp<0><<<MLPB, 256, 0, stream>>>(inputs, xbf, wtb,            bs,       gs,       bes,       nullptr);
    k_gather_bb<<<25000, 256, 0, stream>>>(xbf, rowptr, eidx, xbf + 64);
    // layer 1
    k_mlp<1><<<MLPB, 256, 0, stream>>>(nullptr, xbf, wtb + 8192,    bs + 64,  gs + 64,  bes + 64,  nullptr);
    k_gather_bb<<<25000, 256, 0, stream>>>(xbf, rowptr, eidx, xbf + 64);
    // layer 2: f32 h -> out[n][0:64], bf16 h -> xbf
    k_mlp<2><<<MLPB, 256, 0, stream>>>(nullptr, xbf, wtb + 16384,   bs + 128, gs + 128, bes + 128, out);
    k_gather_bf<<<25000, 256, 0, stream>>>(xbf, rowptr, eidx, out);
}

// Round 9
// 240.143 us; speedup vs baseline: 1.5936x; 1.0922x over previous
//
#include <hip/hip_runtime.h>

#define NN 100000
#define NE 1600000
#define INF 128
#define HID 64
#define LN_EPS 1e-5f

#define BINB 9
#define BINSZ 512
#define NBIN 196
#define FILLB 512

typedef unsigned short u16;
typedef __attribute__((ext_vector_type(8))) short bf16x8;
typedef __attribute__((ext_vector_type(4))) float f32x4;

#define SAP 136   // padded LDS row stride (bf16 elems)

__device__ __forceinline__ u16 f2bf(float f) {
    unsigned u = __float_as_uint(f);
    return (u16)((u + 0x7FFFu + ((u >> 16) & 1u)) >> 16);
}
__device__ __forceinline__ unsigned pack2bf(float a, float b) {
    unsigned ua = __float_as_uint(a), ub = __float_as_uint(b);
    ua = (ua + 0x7FFFu + ((ua >> 16) & 1u)) >> 16;
    ub = (ub + 0x7FFFu + ((ub >> 16) & 1u)) >> 16;
    return ua | (ub << 16);
}

// ---------------- CSR build via binned counting sort ----------------

__global__ __launch_bounds__(256) void k_zero(int* __restrict__ bincnt) {
    int i = threadIdx.x;
    if (i < NBIN) bincnt[i] = 0;
}

__global__ __launch_bounds__(256) void k_binhist(const int* __restrict__ dst, int* __restrict__ bincnt) {
    __shared__ int h[NBIN];
    for (int i = threadIdx.x; i < NBIN; i += 256) h[i] = 0;
    __syncthreads();
    int stride = gridDim.x * 256;
    for (int e = blockIdx.x * 256 + threadIdx.x; e < NE; e += stride)
        atomicAdd(&h[dst[e] >> BINB], 1);
    __syncthreads();
    for (int i = threadIdx.x; i < NBIN; i += 256)
        if (h[i]) atomicAdd(&bincnt[i], h[i]);
}

__global__ __launch_bounds__(256) void k_binscan(const int* __restrict__ bincnt, int* __restrict__ binptr,
                                                 int* __restrict__ bincur, int* __restrict__ rowptr) {
    int tid = threadIdx.x, lane = tid & 63, wid = tid >> 6;
    int x = (tid < NBIN) ? bincnt[tid] : 0;
    int v = x;
    #pragma unroll
    for (int d = 1; d < 64; d <<= 1) { int y = __shfl_up(v, d); if (lane >= d) v += y; }
    __shared__ int wsum[4];
    if (lane == 63) wsum[wid] = v;
    __syncthreads();
    int add = 0;
    for (int w = 0; w < wid; ++w) add += wsum[w];
    int excl = v + add - x;
    if (tid < NBIN) { binptr[tid] = excl; bincur[tid] = excl; }
    if (tid == 0) { binptr[NBIN] = NE; rowptr[NN] = NE; }
}

__global__ __launch_bounds__(256) void k_binfill(const int* __restrict__ src, const int* __restrict__ dst,
                                                 int* __restrict__ bincur, unsigned* __restrict__ binpair) {
    __shared__ int cnt[NBIN];
    __shared__ int base[NBIN];
    __shared__ int cur[NBIN];
    int tid = threadIdx.x;
    const int chunk = (NE + FILLB - 1) / FILLB;
    int s = blockIdx.x * chunk;
    int t = min(s + chunk, NE);

    for (int i = tid; i < NBIN; i += 256) cnt[i] = 0;
    __syncthreads();
    for (int e = s + tid; e < t; e += 256) atomicAdd(&cnt[dst[e] >> BINB], 1);
    __syncthreads();
    for (int i = tid; i < NBIN; i += 256) {
        int c = cnt[i];
        base[i] = c ? atomicAdd(&bincur[i], c) : 0;
        cur[i] = 0;
    }
    __syncthreads();
    for (int e = s + tid; e < t; e += 256) {
        int d = dst[e];
        int b = d >> BINB;
        int pos = base[b] + atomicAdd(&cur[b], 1);
        binpair[pos] = ((unsigned)src[e] << BINB) | (unsigned)(d & (BINSZ - 1));
    }
}

__global__ __launch_bounds__(256) void k_binsort(const unsigned* __restrict__ binpair,
                                                 const int* __restrict__ binptr,
                                                 int* __restrict__ rowptr, int* __restrict__ eidx) {
    __shared__ int cnt[BINSZ];
    __shared__ int ofs[BINSZ];
    __shared__ int cur[BINSZ];
    int tid = threadIdx.x, lane = tid & 63, wid = tid >> 6;
    int b = blockIdx.x;
    int s = binptr[b], t = binptr[b + 1];

    cnt[tid] = 0; cnt[tid + 256] = 0;
    __syncthreads();
    for (int e = s + tid; e < t; e += 256) atomicAdd(&cnt[binpair[e] & (BINSZ - 1)], 1);
    __syncthreads();

    int a0 = cnt[2 * tid], a1 = cnt[2 * tid + 1];
    int ps = a0 + a1;
    int v = ps;
    #pragma unroll
    for (int d = 1; d < 64; d <<= 1) { int y = __shfl_up(v, d); if (lane >= d) v += y; }
    __shared__ int wsum[4];
    if (lane == 63) wsum[wid] = v;
    __syncthreads();
    int add = 0;
    for (int w = 0; w < wid; ++w) add += wsum[w];
    int excl = v + add - ps;
    ofs[2 * tid] = excl; ofs[2 * tid + 1] = excl + a0;
    cur[2 * tid] = excl; cur[2 * tid + 1] = excl + a0;
    __syncthreads();

    int nodeBase = b << BINB;
    #pragma unroll
    for (int j = 0; j < 2; ++j) {
        int i = tid + j * 256;
        int n = nodeBase + i;
        if (n < NN) rowptr[n] = s + ofs[i];
    }

    for (int e = s + tid; e < t; e += 256) {
        unsigned p = binpair[e];
        int l = p & (BINSZ - 1);
        int pos = s + atomicAdd(&cur[l], 1);
        eidx[pos] = (int)(p >> BINB);
    }
}

// ---------------- W convert: f32 [128][64] -> bf16 transposed [64][128] ----------------

__global__ __launch_bounds__(256) void k_wconv(const float* __restrict__ Ws, u16* __restrict__ wtb) {
    int L = blockIdx.x, tid = threadIdx.x;
    int c = tid & 63, k0 = (tid >> 6) * 32;
    const float* W = Ws + (size_t)L * INF * HID;
    alignas(16) u16 tmp[32];
    #pragma unroll
    for (int k = 0; k < 32; ++k) tmp[k] = f2bf(W[(size_t)(k0 + k) * HID + c]);
    u16* dstp = wtb + (size_t)L * HID * INF + (size_t)c * INF + k0;
    #pragma unroll
    for (int j = 0; j < 4; ++j)
        *(uint4*)(dstp + j * 8) = *(uint4*)&tmp[j * 8];
}

// ---------------- MFMA Linear + LayerNorm + ReLU ----------------

template<int KIND>
__global__ __launch_bounds__(256) void k_mlp(
    const float* __restrict__ fin,
    u16* xbf,
    const u16* __restrict__ wtb,
    const float* __restrict__ bias, const float* __restrict__ gam, const float* __restrict__ bet,
    float* __restrict__ fout)
{
    __shared__ u16 sA[64 * SAP];
    __shared__ u16 sB[64 * SAP];

    const int tid = threadIdx.x, lane = tid & 63;
    const int w = __builtin_amdgcn_readfirstlane(tid >> 6);
    const int node0 = blockIdx.x * 64;

    if (KIND == 0) {
        #pragma unroll
        for (int j = 0; j < 8; ++j) {
            int f4 = tid + j * 256;
            int nl = f4 >> 5, k4 = f4 & 31;
            int n = node0 + nl; if (n >= NN) n = NN - 1;
            float4 v = *(const float4*)(fin + (size_t)n * INF + k4 * 4);
            *(uint2*)&sA[nl * SAP + k4 * 4] = make_uint2(pack2bf(v.x, v.y), pack2bf(v.z, v.w));
        }
    } else {
        #pragma unroll
        for (int j = 0; j < 4; ++j) {
            int ch = tid + j * 256;
            int nl = ch >> 4, c8 = ch & 15;
            int n = node0 + nl; if (n >= NN) n = NN - 1;
            *(uint4*)&sA[nl * SAP + c8 * 8] = *(const uint4*)(xbf + (size_t)n * INF + c8 * 8);
        }
    }
    #pragma unroll
    for (int j = 0; j < 4; ++j) {
        int ch = tid + j * 256;
        int r = ch >> 4, k8 = ch & 15;
        *(uint4*)&sB[r * SAP + k8 * 8] = *(const uint4*)(wtb + (size_t)r * INF + k8 * 8);
    }

    const int cl = lane & 15;
    float bC[4], gC[4], tC[4];
    #pragma unroll
    for (int nt = 0; nt < 4; ++nt) {
        int c = nt * 16 + cl;
        bC[nt] = bias[c]; gC[nt] = gam[c]; tC[nt] = bet[c];
    }

    __syncthreads();

    f32x4 acc[4] = {(f32x4)0.f, (f32x4)0.f, (f32x4)0.f, (f32x4)0.f};
    const int kg = (lane >> 4) * 8;
    #pragma unroll
    for (int kk = 0; kk < 4; ++kk) {
        bf16x8 a = *(const bf16x8*)&sA[(w * 16 + cl) * SAP + kk * 32 + kg];
        #pragma unroll
        for (int nt = 0; nt < 4; ++nt) {
            bf16x8 b = *(const bf16x8*)&sB[(nt * 16 + cl) * SAP + kk * 32 + kg];
            acc[nt] = __builtin_amdgcn_mfma_f32_16x16x32_bf16(a, b, acc[nt], 0, 0, 0);
        }
    }

    #pragma unroll
    for (int nt = 0; nt < 4; ++nt)
        #pragma unroll
        for (int r = 0; r < 4; ++r) acc[nt][r] += bC[nt];

    float mu[4], rs[4];
    #pragma unroll
    for (int r = 0; r < 4; ++r) {
        float s = acc[0][r] + acc[1][r] + acc[2][r] + acc[3][r];
        float q = acc[0][r]*acc[0][r] + acc[1][r]*acc[1][r] + acc[2][r]*acc[2][r] + acc[3][r]*acc[3][r];
        #pragma unroll
        for (int m = 1; m < 16; m <<= 1) { s += __shfl_xor(s, m); q += __shfl_xor(q, m); }
        mu[r] = s * 0.015625f;
        float var = fmaxf(q * 0.015625f - mu[r] * mu[r], 0.f);
        rs[r] = rsqrtf(var + LN_EPS);
    }

    #pragma unroll
    for (int nt = 0; nt < 4; ++nt) {
        int c = nt * 16 + cl;
        #pragma unroll
        for (int r = 0; r < 4; ++r) {
            int row = w * 16 + (lane >> 4) * 4 + r;
            float o = fmaxf((acc[nt][r] - mu[r]) * rs[r] * gC[nt] + tC[nt], 0.f);
            sA[row * SAP + c] = f2bf(o);
            if (KIND == 2) {
                int n = node0 + row;
                if (n < NN) fout[(size_t)n * 128 + c] = o;
            }
        }
    }

    #pragma unroll
    for (int i = 0; i < 2; ++i) {
        int ch = lane + i * 64;
        int r16 = ch >> 3, c8 = ch & 7;
        int row = w * 16 + r16;
        int n = node0 + row;
        if (n < NN)
            *(uint4*)(xbf + (size_t)n * INF + c8 * 8) = *(const uint4*)&sA[row * SAP + c8 * 8];
    }
}

// ---------------- per-dst segment max over bf16 rows ----------------
// Wave = 1 dst node, split into 4 groups of 16 lanes; each group processes a
// different edge (lane = 4 features via uint2). 4 rows (512B) per load instr,
// 4-deep unroll => 16 edges (2KB) in flight per wave. 2 shfl_xor rounds combine.

#define GMAX4(v) { m0 = max(m0, v.x & 0xFFFFu); m1 = max(m1, v.x >> 16); \
                   m2 = max(m2, v.y & 0xFFFFu); m3 = max(m3, v.y >> 16); }

__global__ __launch_bounds__(256) void k_gather_bb(
    const u16* __restrict__ hb, const int* __restrict__ rowptr,
    const int* __restrict__ eidx, u16* __restrict__ aggb)
{
    int lane = threadIdx.x & 63;
    int n = blockIdx.x * 4 + (threadIdx.x >> 6);
    if (n >= NN) return;
    int start = rowptr[n], end = rowptr[n + 1];
    int g = lane >> 4, fl = lane & 15;
    unsigned m0 = 0, m1 = 0, m2 = 0, m3 = 0;

    if (start == end) {
        uint2 v = *(const uint2*)(hb + (size_t)n * 128 + fl * 4);
        GMAX4(v);
    } else {
        int e = start + g;
        while (e + 12 < end) {
            int i0 = eidx[e], i1 = eidx[e + 4], i2 = eidx[e + 8], i3 = eidx[e + 12];
            uint2 a = *(const uint2*)(hb + (size_t)i0 * 128 + fl * 4);
            uint2 b = *(const uint2*)(hb + (size_t)i1 * 128 + fl * 4);
            uint2 c = *(const uint2*)(hb + (size_t)i2 * 128 + fl * 4);
            uint2 d = *(const uint2*)(hb + (size_t)i3 * 128 + fl * 4);
            GMAX4(a); GMAX4(b); GMAX4(c); GMAX4(d);
            e += 16;
        }
        for (; e < end; e += 4) {
            int i = eidx[e];
            uint2 v = *(const uint2*)(hb + (size_t)i * 128 + fl * 4);
            GMAX4(v);
        }
    }

    #pragma unroll
    for (int d = 16; d <= 32; d <<= 1) {
        m0 = max(m0, (unsigned)__shfl_xor((int)m0, d));
        m1 = max(m1, (unsigned)__shfl_xor((int)m1, d));
        m2 = max(m2, (unsigned)__shfl_xor((int)m2, d));
        m3 = max(m3, (unsigned)__shfl_xor((int)m3, d));
    }
    if (g == 0) {
        uint2 o; o.x = m0 | (m1 << 16); o.y = m2 | (m3 << 16);
        *(uint2*)(aggb + (size_t)n * 128 + fl * 4) = o;
    }
}

__global__ __launch_bounds__(256) void k_gather_bf(
    const u16* __restrict__ hb, const int* __restrict__ rowptr,
    const int* __restrict__ eidx, float* __restrict__ out)
{
    int lane = threadIdx.x & 63;
    int n = blockIdx.x * 4 + (threadIdx.x >> 6);
    if (n >= NN) return;
    int start = rowptr[n], end = rowptr[n + 1];
    int g = lane >> 4, fl = lane & 15;

    if (start == end) {
        if (g == 0) {   // exact f32 self feature
            float4 v = *(const float4*)(out + (size_t)n * 128 + fl * 4);
            *(float4*)(out + (size_t)n * 128 + 64 + fl * 4) = v;
        }
        return;
    }

    unsigned m0 = 0, m1 = 0, m2 = 0, m3 = 0;
    int e = start + g;
    while (e + 12 < end) {
        int i0 = eidx[e], i1 = eidx[e + 4], i2 = eidx[e + 8], i3 = eidx[e + 12];
        uint2 a = *(const uint2*)(hb + (size_t)i0 * 128 + fl * 4);
        uint2 b = *(const uint2*)(hb + (size_t)i1 * 128 + fl * 4);
        uint2 c = *(const uint2*)(hb + (size_t)i2 * 128 + fl * 4);
        uint2 d = *(const uint2*)(hb + (size_t)i3 * 128 + fl * 4);
        GMAX4(a); GMAX4(b); GMAX4(c); GMAX4(d);
        e += 16;
    }
    for (; e < end; e += 4) {
        int i = eidx[e];
        uint2 v = *(const uint2*)(hb + (size_t)i * 128 + fl * 4);
        GMAX4(v);
    }

    #pragma unroll
    for (int d = 16; d <= 32; d <<= 1) {
        m0 = max(m0, (unsigned)__shfl_xor((int)m0, d));
        m1 = max(m1, (unsigned)__shfl_xor((int)m1, d));
        m2 = max(m2, (unsigned)__shfl_xor((int)m2, d));
        m3 = max(m3, (unsigned)__shfl_xor((int)m3, d));
    }
    if (g == 0) {
        float4 o = make_float4(__uint_as_float(m0 << 16), __uint_as_float(m1 << 16),
                               __uint_as_float(m2 << 16), __uint_as_float(m3 << 16));
        *(float4*)(out + (size_t)n * 128 + 64 + fl * 4) = o;
    }
}

// ---------------- launch ----------------

extern "C" void kernel_launch(void* const* d_in, const int* in_sizes, int n_in,
                              void* d_out, int out_size, void* d_ws, size_t ws_size,
                              hipStream_t stream) {
    const float* inputs = (const float*)d_in[0];
    const int*   src    = (const int*)d_in[1];
    const int*   dst    = (const int*)d_in[2];
    const float* Ws     = (const float*)d_in[3];
    const float* bs     = (const float*)d_in[4];
    const float* gs     = (const float*)d_in[5];
    const float* bes    = (const float*)d_in[6];
    float* out = (float*)d_out;

    char* w = (char*)d_ws;
    int* bincnt = (int*)w; w += 256 * 4;
    int* binptr = (int*)w; w += 256 * 4;
    int* bincur = (int*)w; w += 256 * 4;
    int* rowptr = (int*)w; w += (size_t)(NN + 1) * 4;
    int* eidx   = (int*)w; w += (size_t)NE * 4;
    uintptr_t a = (uintptr_t)w; a = (a + 255) & ~(uintptr_t)255; w = (char*)a;
    u16* wtb     = (u16*)w; w += 3 * (size_t)INF * HID * 2;
    u16* xbf     = (u16*)w; w += (size_t)NN * INF * 2;
    unsigned* binpair = (unsigned*)w; w += (size_t)NE * 4;

    const int MLPB = (NN + 63) / 64;

    // CSR build
    k_zero   <<<1,     256, 0, stream>>>(bincnt);
    k_binhist<<<391,   256, 0, stream>>>(dst, bincnt);
    k_binscan<<<1,     256, 0, stream>>>(bincnt, binptr, bincur, rowptr);
    k_binfill<<<FILLB, 256, 0, stream>>>(src, dst, bincur, binpair);
    k_binsort<<<NBIN,  256, 0, stream>>>(binpair, binptr, rowptr, eidx);

    // weights -> bf16 transposed
    k_wconv<<<3, 256, 0, stream>>>(Ws, wtb);

    // layer 0
    k_mlp<0><<<MLPB, 256, 0, stream>>>(inputs, xbf, wtb,            bs,       gs,       bes,       nullptr);
    k_gather_bb<<<25000, 256, 0, stream>>>(xbf, rowptr, eidx, xbf + 64);
    // layer 1
    k_mlp<1><<<MLPB, 256, 0, stream>>>(nullptr, xbf, wtb + 8192,    bs + 64,  gs + 64,  bes + 64,  nullptr);
    k_gather_bb<<<25000, 256, 0, stream>>>(xbf, rowptr, eidx, xbf + 64);
    // layer 2
    k_mlp<2><<<MLPB, 256, 0, stream>>>(nullptr, xbf, wtb + 16384,   bs + 128, gs + 128, bes + 128, out);
    k_gather_bf<<<25000, 256, 0, stream>>>(xbf, rowptr, eidx, out);
}

// Round 10
// 190.127 us; speedup vs baseline: 2.0128x; 1.2631x over previous
//
#include <hip/hip_runtime.h>

#define NN 100000
#define NE 1600000
#define INF 128
#define HID 64
#define LN_EPS 1e-5f

#define BINB 9
#define BINSZ 512
#define NBIN 196
#define FILLB 512
#define BCAP 9250   // fixed bin slot capacity (Poisson(8163) + 12 sigma)

typedef unsigned short u16;
typedef __attribute__((ext_vector_type(8))) short bf16x8;
typedef __attribute__((ext_vector_type(4))) float f32x4;

#define SAP 136   // padded LDS row stride (bf16 elems)

__device__ __forceinline__ u16 f2bf(float f) {
    unsigned u = __float_as_uint(f);
    return (u16)((u + 0x7FFFu + ((u >> 16) & 1u)) >> 16);
}
__device__ __forceinline__ unsigned pack2bf(float a, float b) {
    unsigned ua = __float_as_uint(a), ub = __float_as_uint(b);
    ua = (ua + 0x7FFFu + ((ua >> 16) & 1u)) >> 16;
    ub = (ub + 0x7FFFu + ((ub >> 16) & 1u)) >> 16;
    return ua | (ub << 16);
}

// ---------------- CSR build: slotted binned counting sort ----------------

__global__ __launch_bounds__(256) void k_zero(int* __restrict__ bincur) {
    int i = threadIdx.x;
    if (i < NBIN) bincur[i] = 0;
}

// block-privatized fill into fixed slots: bin b occupies [b*BCAP, b*BCAP+count)
__global__ __launch_bounds__(256) void k_binfill(const int* __restrict__ src, const int* __restrict__ dst,
                                                 int* __restrict__ bincur, unsigned* __restrict__ binpair) {
    __shared__ int cnt[NBIN];
    __shared__ int base[NBIN];
    __shared__ int cur[NBIN];
    int tid = threadIdx.x;
    const int chunk = (NE + FILLB - 1) / FILLB;
    int s = blockIdx.x * chunk;
    int t = min(s + chunk, NE);

    for (int i = tid; i < NBIN; i += 256) cnt[i] = 0;
    __syncthreads();
    for (int e = s + tid; e < t; e += 256) atomicAdd(&cnt[dst[e] >> BINB], 1);
    __syncthreads();
    for (int i = tid; i < NBIN; i += 256) {
        int c = cnt[i];
        base[i] = c ? atomicAdd(&bincur[i], c) : 0;
        cur[i] = 0;
    }
    __syncthreads();
    for (int e = s + tid; e < t; e += 256) {
        int d = dst[e];
        int b = d >> BINB;
        int pos = base[b] + atomicAdd(&cur[b], 1);
        binpair[(size_t)b * BCAP + pos] = ((unsigned)src[e] << BINB) | (unsigned)(d & (BINSZ - 1));
    }
}

// per-bin counting sort; emits rowptr[n] (slotted) + deg[n] + eidx
__global__ __launch_bounds__(256) void k_binsort(const unsigned* __restrict__ binpair,
                                                 const int* __restrict__ bincur,
                                                 int* __restrict__ rowptr, int* __restrict__ deg,
                                                 int* __restrict__ eidx) {
    __shared__ int cnt[BINSZ];
    __shared__ int ofs[BINSZ];
    __shared__ int cur[BINSZ];
    int tid = threadIdx.x, lane = tid & 63, wid = tid >> 6;
    int b = blockIdx.x;
    int s = b * BCAP;
    int t = s + bincur[b];

    cnt[tid] = 0; cnt[tid + 256] = 0;
    __syncthreads();
    for (int e = s + tid; e < t; e += 256) atomicAdd(&cnt[binpair[e] & (BINSZ - 1)], 1);
    __syncthreads();

    int a0 = cnt[2 * tid], a1 = cnt[2 * tid + 1];
    int ps = a0 + a1;
    int v = ps;
    #pragma unroll
    for (int d = 1; d < 64; d <<= 1) { int y = __shfl_up(v, d); if (lane >= d) v += y; }
    __shared__ int wsum[4];
    if (lane == 63) wsum[wid] = v;
    __syncthreads();
    int add = 0;
    for (int w = 0; w < wid; ++w) add += wsum[w];
    int excl = v + add - ps;
    ofs[2 * tid] = excl; ofs[2 * tid + 1] = excl + a0;
    cur[2 * tid] = excl; cur[2 * tid + 1] = excl + a0;
    __syncthreads();

    int nodeBase = b << BINB;
    #pragma unroll
    for (int j = 0; j < 2; ++j) {
        int i = tid + j * 256;
        int n = nodeBase + i;
        if (n < NN) { rowptr[n] = s + ofs[i]; deg[n] = cnt[i]; }
    }

    for (int e = s + tid; e < t; e += 256) {
        unsigned p = binpair[e];
        int l = p & (BINSZ - 1);
        int pos = s + atomicAdd(&cur[l], 1);
        eidx[pos] = (int)(p >> BINB);
    }
}

// ---------------- W convert: f32 [128][64] -> bf16 transposed [64][128] ----------------

__global__ __launch_bounds__(256) void k_wconv(const float* __restrict__ Ws, u16* __restrict__ wtb) {
    int L = blockIdx.x, tid = threadIdx.x;
    int c = tid & 63, k0 = (tid >> 6) * 32;
    const float* W = Ws + (size_t)L * INF * HID;
    alignas(16) u16 tmp[32];
    #pragma unroll
    for (int k = 0; k < 32; ++k) tmp[k] = f2bf(W[(size_t)(k0 + k) * HID + c]);
    u16* dstp = wtb + (size_t)L * HID * INF + (size_t)c * INF + k0;
    #pragma unroll
    for (int j = 0; j < 4; ++j)
        *(uint4*)(dstp + j * 8) = *(uint4*)&tmp[j * 8];
}

// ---------------- MFMA Linear + LayerNorm + ReLU ----------------

template<int KIND>
__global__ __launch_bounds__(256) void k_mlp(
    const float* __restrict__ fin,
    u16* xbf,
    const u16* __restrict__ wtb,
    const float* __restrict__ bias, const float* __restrict__ gam, const float* __restrict__ bet,
    float* __restrict__ fout)
{
    __shared__ u16 sA[64 * SAP];
    __shared__ u16 sB[64 * SAP];

    const int tid = threadIdx.x, lane = tid & 63;
    const int w = __builtin_amdgcn_readfirstlane(tid >> 6);
    const int node0 = blockIdx.x * 64;

    if (KIND == 0) {
        #pragma unroll
        for (int j = 0; j < 8; ++j) {
            int f4 = tid + j * 256;
            int nl = f4 >> 5, k4 = f4 & 31;
            int n = node0 + nl; if (n >= NN) n = NN - 1;
            float4 v = *(const float4*)(fin + (size_t)n * INF + k4 * 4);
            *(uint2*)&sA[nl * SAP + k4 * 4] = make_uint2(pack2bf(v.x, v.y), pack2bf(v.z, v.w));
        }
    } else {
        #pragma unroll
        for (int j = 0; j < 4; ++j) {
            int ch = tid + j * 256;
            int nl = ch >> 4, c8 = ch & 15;
            int n = node0 + nl; if (n >= NN) n = NN - 1;
            *(uint4*)&sA[nl * SAP + c8 * 8] = *(const uint4*)(xbf + (size_t)n * INF + c8 * 8);
        }
    }
    #pragma unroll
    for (int j = 0; j < 4; ++j) {
        int ch = tid + j * 256;
        int r = ch >> 4, k8 = ch & 15;
        *(uint4*)&sB[r * SAP + k8 * 8] = *(const uint4*)(wtb + (size_t)r * INF + k8 * 8);
    }

    const int cl = lane & 15;
    float bC[4], gC[4], tC[4];
    #pragma unroll
    for (int nt = 0; nt < 4; ++nt) {
        int c = nt * 16 + cl;
        bC[nt] = bias[c]; gC[nt] = gam[c]; tC[nt] = bet[c];
    }

    __syncthreads();

    f32x4 acc[4] = {(f32x4)0.f, (f32x4)0.f, (f32x4)0.f, (f32x4)0.f};
    const int kg = (lane >> 4) * 8;
    #pragma unroll
    for (int kk = 0; kk < 4; ++kk) {
        bf16x8 a = *(const bf16x8*)&sA[(w * 16 + cl) * SAP + kk * 32 + kg];
        #pragma unroll
        for (int nt = 0; nt < 4; ++nt) {
            bf16x8 b = *(const bf16x8*)&sB[(nt * 16 + cl) * SAP + kk * 32 + kg];
            acc[nt] = __builtin_amdgcn_mfma_f32_16x16x32_bf16(a, b, acc[nt], 0, 0, 0);
        }
    }

    #pragma unroll
    for (int nt = 0; nt < 4; ++nt)
        #pragma unroll
        for (int r = 0; r < 4; ++r) acc[nt][r] += bC[nt];

    float mu[4], rs[4];
    #pragma unroll
    for (int r = 0; r < 4; ++r) {
        float s = acc[0][r] + acc[1][r] + acc[2][r] + acc[3][r];
        float q = acc[0][r]*acc[0][r] + acc[1][r]*acc[1][r] + acc[2][r]*acc[2][r] + acc[3][r]*acc[3][r];
        #pragma unroll
        for (int m = 1; m < 16; m <<= 1) { s += __shfl_xor(s, m); q += __shfl_xor(q, m); }
        mu[r] = s * 0.015625f;
        float var = fmaxf(q * 0.015625f - mu[r] * mu[r], 0.f);
        rs[r] = rsqrtf(var + LN_EPS);
    }

    #pragma unroll
    for (int nt = 0; nt < 4; ++nt) {
        int c = nt * 16 + cl;
        #pragma unroll
        for (int r = 0; r < 4; ++r) {
            int row = w * 16 + (lane >> 4) * 4 + r;
            float o = fmaxf((acc[nt][r] - mu[r]) * rs[r] * gC[nt] + tC[nt], 0.f);
            sA[row * SAP + c] = f2bf(o);
            if (KIND == 2) {
                int n = node0 + row;
                if (n < NN) fout[(size_t)n * 128 + c] = o;
            }
        }
    }

    #pragma unroll
    for (int i = 0; i < 2; ++i) {
        int ch = lane + i * 64;
        int r16 = ch >> 3, c8 = ch & 7;
        int row = w * 16 + r16;
        int n = node0 + row;
        if (n < NN)
            *(uint4*)(xbf + (size_t)n * INF + c8 * 8) = *(const uint4*)&sA[row * SAP + c8 * 8];
    }
}

// ---------------- per-dst segment max over bf16 rows ----------------
// group(16 lanes) = 1 dst node, 4 nodes/wave, 16 nodes/block. Lane owns 4
// features (uint2) end-to-end: no cross-lane combine. 8-deep unrolled edge
// loop => 8 row loads in flight per lane. rowptr/deg staged via lane<4 + shfl.

#define GMAX4(v) { m0 = max(m0, v.x & 0xFFFFu); m1 = max(m1, v.x >> 16); \
                   m2 = max(m2, v.y & 0xFFFFu); m3 = max(m3, v.y >> 16); }

__global__ __launch_bounds__(256) void k_gather_bb(
    const u16* __restrict__ hb, const int* __restrict__ rowptr, const int* __restrict__ deg,
    const int* __restrict__ eidx, u16* __restrict__ aggb)
{
    int tid = threadIdx.x, lane = tid & 63, wid = tid >> 6;
    int nw0 = blockIdx.x * 16 + wid * 4;
    int g = lane >> 4, fl = lane & 15;
    int n = nw0 + g;

    int rp = (lane < 4) ? rowptr[nw0 + lane] : 0;
    int dv = (lane < 4) ? deg[nw0 + lane] : 0;
    int start = __shfl(rp, g);
    int dg    = __shfl(dv, g);

    unsigned m0 = 0, m1 = 0, m2 = 0, m3 = 0;
    if (dg == 0) {
        uint2 v = *(const uint2*)(hb + (size_t)n * 128 + fl * 4);
        m0 = v.x & 0xFFFFu; m1 = v.x >> 16; m2 = v.y & 0xFFFFu; m3 = v.y >> 16;
    } else {
        int e = start, endv = start + dg;
        for (; e + 8 <= endv; e += 8) {
            int i0 = eidx[e],     i1 = eidx[e + 1], i2 = eidx[e + 2], i3 = eidx[e + 3];
            int i4 = eidx[e + 4], i5 = eidx[e + 5], i6 = eidx[e + 6], i7 = eidx[e + 7];
            uint2 v0 = *(const uint2*)(hb + (size_t)i0 * 128 + fl * 4);
            uint2 v1 = *(const uint2*)(hb + (size_t)i1 * 128 + fl * 4);
            uint2 v2 = *(const uint2*)(hb + (size_t)i2 * 128 + fl * 4);
            uint2 v3 = *(const uint2*)(hb + (size_t)i3 * 128 + fl * 4);
            uint2 v4 = *(const uint2*)(hb + (size_t)i4 * 128 + fl * 4);
            uint2 v5 = *(const uint2*)(hb + (size_t)i5 * 128 + fl * 4);
            uint2 v6 = *(const uint2*)(hb + (size_t)i6 * 128 + fl * 4);
            uint2 v7 = *(const uint2*)(hb + (size_t)i7 * 128 + fl * 4);
            GMAX4(v0); GMAX4(v1); GMAX4(v2); GMAX4(v3);
            GMAX4(v4); GMAX4(v5); GMAX4(v6); GMAX4(v7);
        }
        for (; e < endv; ++e) {
            uint2 v = *(const uint2*)(hb + (size_t)eidx[e] * 128 + fl * 4);
            GMAX4(v);
        }
    }
    uint2 o; o.x = m0 | (m1 << 16); o.y = m2 | (m3 << 16);
    *(uint2*)(aggb + (size_t)n * 128 + fl * 4) = o;
}

__global__ __launch_bounds__(256) void k_gather_bf(
    const u16* __restrict__ hb, const int* __restrict__ rowptr, const int* __restrict__ deg,
    const int* __restrict__ eidx, float* __restrict__ out)
{
    int tid = threadIdx.x, lane = tid & 63, wid = tid >> 6;
    int nw0 = blockIdx.x * 16 + wid * 4;
    int g = lane >> 4, fl = lane & 15;
    int n = nw0 + g;

    int rp = (lane < 4) ? rowptr[nw0 + lane] : 0;
    int dv = (lane < 4) ? deg[nw0 + lane] : 0;
    int start = __shfl(rp, g);
    int dg    = __shfl(dv, g);

    if (dg == 0) {   // exact f32 self feature
        float4 v = *(const float4*)(out + (size_t)n * 128 + fl * 4);
        *(float4*)(out + (size_t)n * 128 + 64 + fl * 4) = v;
        return;
    }

    unsigned m0 = 0, m1 = 0, m2 = 0, m3 = 0;
    int e = start, endv = start + dg;
    for (; e + 8 <= endv; e += 8) {
        int i0 = eidx[e],     i1 = eidx[e + 1], i2 = eidx[e + 2], i3 = eidx[e + 3];
        int i4 = eidx[e + 4], i5 = eidx[e + 5], i6 = eidx[e + 6], i7 = eidx[e + 7];
        uint2 v0 = *(const uint2*)(hb + (size_t)i0 * 128 + fl * 4);
        uint2 v1 = *(const uint2*)(hb + (size_t)i1 * 128 + fl * 4);
        uint2 v2 = *(const uint2*)(hb + (size_t)i2 * 128 + fl * 4);
        uint2 v3 = *(const uint2*)(hb + (size_t)i3 * 128 + fl * 4);
        uint2 v4 = *(const uint2*)(hb + (size_t)i4 * 128 + fl * 4);
        uint2 v5 = *(const uint2*)(hb + (size_t)i5 * 128 + fl * 4);
        uint2 v6 = *(const uint2*)(hb + (size_t)i6 * 128 + fl * 4);
        uint2 v7 = *(const uint2*)(hb + (size_t)i7 * 128 + fl * 4);
        GMAX4(v0); GMAX4(v1); GMAX4(v2); GMAX4(v3);
        GMAX4(v4); GMAX4(v5); GMAX4(v6); GMAX4(v7);
    }
    for (; e < endv; ++e) {
        uint2 v = *(const uint2*)(hb + (size_t)eidx[e] * 128 + fl * 4);
        GMAX4(v);
    }
    float4 o = make_float4(__uint_as_float(m0 << 16), __uint_as_float(m1 << 16),
                           __uint_as_float(m2 << 16), __uint_as_float(m3 << 16));
    *(float4*)(out + (size_t)n * 128 + 64 + fl * 4) = o;
}

// ---------------- launch ----------------

extern "C" void kernel_launch(void* const* d_in, const int* in_sizes, int n_in,
                              void* d_out, int out_size, void* d_ws, size_t ws_size,
                              hipStream_t stream) {
    const float* inputs = (const float*)d_in[0];
    const int*   src    = (const int*)d_in[1];
    const int*   dst    = (const int*)d_in[2];
    const float* Ws     = (const float*)d_in[3];
    const float* bs     = (const float*)d_in[4];
    const float* gs     = (const float*)d_in[5];
    const float* bes    = (const float*)d_in[6];
    float* out = (float*)d_out;

    char* w = (char*)d_ws;
    int* bincur = (int*)w; w += 256 * 4;
    int* rowptr = (int*)w; w += (size_t)(NN + 1) * 4;
    int* deg    = (int*)w; w += (size_t)NN * 4;
    int* eidx   = (int*)w; w += (size_t)NBIN * BCAP * 4;             // 7.25 MB
    uintptr_t a = (uintptr_t)w; a = (a + 255) & ~(uintptr_t)255; w = (char*)a;
    u16* wtb     = (u16*)w; w += 3 * (size_t)INF * HID * 2;
    u16* xbf     = (u16*)w; w += (size_t)NN * INF * 2;               // 25.6 MB
    unsigned* binpair = (unsigned*)w; w += (size_t)NBIN * BCAP * 4;  // 7.25 MB

    const int MLPB = (NN + 63) / 64;   // 1563
    const int GATB = (NN + 15) / 16;   // 6250

    // CSR build (slotted bins: no histogram/scan passes)
    k_zero   <<<1,     256, 0, stream>>>(bincur);
    k_binfill<<<FILLB, 256, 0, stream>>>(src, dst, bincur, binpair);
    k_binsort<<<NBIN,  256, 0, stream>>>(binpair, bincur, rowptr, deg, eidx);

    // weights -> bf16 transposed
    k_wconv<<<3, 256, 0, stream>>>(Ws, wtb);

    // layer 0
    k_mlp<0><<<MLPB, 256, 0, stream>>>(inputs, xbf, wtb,            bs,       gs,       bes,       nullptr);
    k_gather_bb<<<GATB, 256, 0, stream>>>(xbf, rowptr, deg, eidx, xbf + 64);
    // layer 1
    k_mlp<1><<<MLPB, 256, 0, stream>>>(nullptr, xbf, wtb + 8192,    bs + 64,  gs + 64,  bes + 64,  nullptr);
    k_gather_bb<<<GATB, 256, 0, stream>>>(xbf, rowptr, deg, eidx, xbf + 64);
    // layer 2
    k_mlp<2><<<MLPB, 256, 0, stream>>>(nullptr, xbf, wtb + 16384,   bs + 128, gs + 128, bes + 128, out);
    k_gather_bf<<<GATB, 256, 0, stream>>>(xbf, rowptr, deg, eidx, out);
}